// Round 8
// baseline (373.272 us; speedup 1.0000x reference)
//
#include <hip/hip_runtime.h>
#include <hip/hip_bf16.h>

// LSTMFeatureExtractor: 2-layer LSTM (H=64, IN=1, B=2048, T=512) + FC(64->32)+ReLU
// R13 = 16-wave unit-octet split. R12 refuted phase-collision (enforced
// anti-phase = neutral-minus-barrier); the ~680cy/step idle is the serial
// latency chain that 2 lockstep waves/SIMD can't hide. Fix: same total issue,
// twice the carriers: 1024 thr = 8 L0 + 8 L1 waves, each owning 8 units
// (2 n-tiles: t0 = i|f gates, t1 = g|o; lane nq<8 = i/g col, nq>=8 = f/o col).
// L0 wave = 4 MFMAs, L1 = 8; cell split across the lane pair: lo computes
// i*g, one __shfl_xor(8) ships it, hi holds c and finishes f*c+ig, o*tanh(c).
// Branchless gate select: fmaf(selA, rcp(1+exp2(p)), selB) = sig or tanh.
// 4 waves/SIMD at staggered chain depths -> latency finally hideable.

#define HID 64
#define TSTEPS 512
#define MB 8
#define RS 80   // f16 row stride: 160B

typedef _Float16 f16x8 __attribute__((ext_vector_type(8)));
typedef float f32x4 __attribute__((ext_vector_type(4)));

#define KSIG (-1.44269504089f)   // -log2(e)
#define KTANH (2.88539008178f)   // 2*log2(e)

__device__ __forceinline__ float rcp1p(float p) {   // rcp(1 + exp2(p))
    return __builtin_amdgcn_rcpf(1.f + __builtin_amdgcn_exp2f(p));
}

#define MFMA16(A, B, C) __builtin_amdgcn_mfma_f32_16x16x32_f16((A), (B), (C), 0, 0, 0)

__global__ __launch_bounds__(1024) void lstm_feat_kernel(
    const float* __restrict__ x,
    const float* __restrict__ Wih0, const float* __restrict__ Whh0,
    const float* __restrict__ bih0, const float* __restrict__ bhh0,
    const float* __restrict__ Wih1, const float* __restrict__ Whh1,
    const float* __restrict__ bih1, const float* __restrict__ bhh1,
    const float* __restrict__ fcW, const float* __restrict__ fcb,
    float* __restrict__ out)
{
    __shared__ __align__(16) float x_lds[4 * TSTEPS * 2];    // [quad][t][2], 16 KB
    __shared__ __align__(16) _Float16 h0_lds[2][MB * RS];    // H0[t] in slot t&1
    __shared__ __align__(16) _Float16 h1_lds[2][MB * RS];    // H1[s] in slot (s+1)&1
    __shared__ float h1f32[MB * HID];
    __shared__ float fcw_lds[HID * 32];                      // transposed [k][o]
    __shared__ float fcb_lds[32];

    const int tid  = threadIdx.x;
    const int wave = tid >> 6;
    const int lane = tid & 63;
    const int nq   = lane & 15;
    const int quad = lane >> 4;
    const int bbase = blockIdx.x * MB;
    const bool isL1 = (wave >= 8);       // waves 0-7: layer0, 8-15: layer1
    const int oct = (wave & 7) * 8;      // first of this wave's 8 units
    const bool lo = (nq < 8);            // lo: i/g column, hi: f/o column
    const int uu = oct + (nq & 7);       // this lane's unit

    // ---- one-time staging ----
    for (int i = tid; i < TSTEPS * MB; i += 1024) {
        int r = i >> 9, t = i & (TSTEPS - 1);
        x_lds[(r >> 1) * (TSTEPS * 2) + t * 2 + (r & 1)] = x[(bbase + r) * TSTEPS + t];
    }
    for (int i = tid; i < 32 * HID; i += 1024) {
        int o = i >> 6, kk = i & 63;
        fcw_lds[kk * 32 + o] = fcW[i];
    }
    if (tid < 32) fcb_lds[tid] = fcb[tid];
    for (int i = tid; i < 2 * MB * RS; i += 1024) {
        ((_Float16*)h0_lds)[i] = (_Float16)0.f;
        ((_Float16*)h1_lds)[i] = (_Float16)0.f;
    }

    // ---- per-lane n and scale for the 2 tiles (PyTorch gate order i,f,g,o) ----
    int   ntab[2];
    float scl[2];
    #pragma unroll
    for (int t = 0; t < 2; ++t) {
        const int gate = 2 * t + (lo ? 0 : 1);   // t0: i|f, t1: g|o
        ntab[t] = gate * 64 + uu;
        scl[t]  = (gate == 2) ? KTANH : KSIG;
    }
    const float selA = lo ? -2.f : 1.f;   // val = fmaf(selA, r, selB):
    const float selB = lo ?  1.f : 0.f;   //   lo -> 1-2r (tanh), hi -> r (sig)

    // ---- weight fragments, PRE-SCALED ----
    // L0: wf[t][0..1] = Whh0. L1: wf[t][0..1] = Wih1, wf[t][2..3] = Whh1.
    f16x8 wf[2][4];
    float wx0v[2], bsv[2];
    f32x4 cbv[2];
    if (!isL1) {
        #pragma unroll
        for (int t = 0; t < 2; ++t) {
            const int n = ntab[t];
            wx0v[t] = Wih0[n] * scl[t];
            bsv[t]  = (bih0[n] + bhh0[n]) * scl[t];
            #pragma unroll
            for (int ks = 0; ks < 2; ++ks) {
                f16x8 a;
                #pragma unroll
                for (int j = 0; j < 8; ++j)
                    a[j] = (_Float16)(Whh0[n * HID + quad * 8 + ks * 32 + j] * scl[t]);
                wf[t][ks] = a;
            }
        }
    } else {
        #pragma unroll
        for (int t = 0; t < 2; ++t) {
            const int n = ntab[t];
            const float cb = (bih1[n] + bhh1[n]) * scl[t];
            cbv[t] = (f32x4){cb, cb, cb, cb};
            #pragma unroll
            for (int ks = 0; ks < 4; ++ks) {
                const float* W = (ks < 2) ? Wih1 : Whh1;
                const int k0 = quad * 8 + (ks & 1) * 32;
                f16x8 a;
                #pragma unroll
                for (int j = 0; j < 8; ++j)
                    a[j] = (_Float16)(W[n * HID + k0 + j] * scl[t]);
                wf[t][ks] = a;
            }
        }
    }

    // A row m carries h[m>>1]; lane reads A-row nq -> batch nq>>1.
    // D rows quad*4+{0,1} -> batch 2q (elem 0), {2,3} -> 2q+1 (elem 2).
    const int arow = (nq >> 1) * RS + quad * 8;
    const int b0r  = (quad * 2) * RS;
    float c0 = 0.f, c1 = 0.f;            // cell state (meaningful on hi lanes)

    __syncthreads();

// ---- split cell: A0 = tile0 acc (i|f), A1 = tile1 acc (g|o) ----
#define CELL(A0, A1, DST, GUARD) do {                                             \
    float r0a = rcp1p((A0)[0]), r0b = rcp1p((A0)[2]);  /* iv | fv */              \
    float r1a = rcp1p((A1)[0]), r1b = rcp1p((A1)[2]);                             \
    float va = fmaf(selA, r1a, selB), vb = fmaf(selA, r1b, selB); /* gv | ov */   \
    float sa = __shfl_xor(r0a * va, 8);   /* hi lanes receive iv*gv */            \
    float sb = __shfl_xor(r0b * vb, 8);                                           \
    if (GUARD) {                                                                  \
        c0 = fmaf(r0a, c0, sa);  c1 = fmaf(r0b, c1, sb);                          \
        float ha = va * (1.f - 2.f * rcp1p(c0 * KTANH));                          \
        float hb = vb * (1.f - 2.f * rcp1p(c1 * KTANH));                          \
        if (!lo) {                                                                \
            (DST)[b0r + uu]      = (_Float16)ha;                                  \
            (DST)[b0r + RS + uu] = (_Float16)hb;                                  \
        }                                                                         \
    }                                                                             \
} while (0)

// ---- L0 step: H0 slot P + x -> H0 slot Q (4 MFMAs, 2 indep 2-chains) ----
#define L0_STEP(P, Q, XA, XB) do {                                                \
    f16x8 a0 = *(const f16x8*)&h0_lds[P][arow];                                   \
    f16x8 a1 = *(const f16x8*)&h0_lds[P][arow + 32];                              \
    f32x4 A[2];                                                                   \
    __builtin_amdgcn_s_setprio(1);                                                \
    _Pragma("unroll")                                                             \
    for (int t = 0; t < 2; ++t) {                                                 \
        f32x4 C;                                                                  \
        C[0] = fmaf((XA), wx0v[t], bsv[t]); C[1] = 0.f;                           \
        C[2] = fmaf((XB), wx0v[t], bsv[t]); C[3] = 0.f;                           \
        A[t] = MFMA16(a0, wf[t][0], C);                                           \
    }                                                                             \
    _Pragma("unroll")                                                             \
    for (int t = 0; t < 2; ++t) A[t] = MFMA16(a1, wf[t][1], A[t]);                \
    __builtin_amdgcn_s_setprio(0);                                                \
    CELL(A[0], A[1], h0_lds[Q], true);                                            \
} while (0)

// ---- L1 step: H0 slot P, H1 slot P -> H1 slot Q (8 MFMAs, 2 indep 4-chains) ----
#define L1_STEP(P, Q, GUARD) do {                                                 \
    f16x8 a0  = *(const f16x8*)&h0_lds[P][arow];                                  \
    f16x8 a1  = *(const f16x8*)&h0_lds[P][arow + 32];                             \
    f16x8 b0v = *(const f16x8*)&h1_lds[P][arow];                                  \
    f16x8 b1v = *(const f16x8*)&h1_lds[P][arow + 32];                             \
    f32x4 A[2];                                                                   \
    __builtin_amdgcn_s_setprio(1);                                                \
    _Pragma("unroll")                                                             \
    for (int t = 0; t < 2; ++t) A[t] = MFMA16(a0, wf[t][0], cbv[t]);              \
    _Pragma("unroll")                                                             \
    for (int t = 0; t < 2; ++t) A[t] = MFMA16(a1, wf[t][1], A[t]);                \
    _Pragma("unroll")                                                             \
    for (int t = 0; t < 2; ++t) A[t] = MFMA16(b0v, wf[t][2], A[t]);               \
    _Pragma("unroll")                                                             \
    for (int t = 0; t < 2; ++t) A[t] = MFMA16(b1v, wf[t][3], A[t]);               \
    __builtin_amdgcn_s_setprio(0);                                                \
    CELL(A[0], A[1], h1_lds[Q], GUARD);                                           \
} while (0)

    const int xoff = quad * (TSTEPS * 2);

    // ---- peeled k=0,1 (L1 k==0 guarded: H1[0] stays the pre-zeroed state) ----
    {
        const f32x4 xv = *(const f32x4*)&x_lds[xoff + 0];
        if (!isL1) L0_STEP(0, 1, xv[0], xv[1]); else L1_STEP(0, 1, false);
        __syncthreads();
        if (!isL1) L0_STEP(1, 0, xv[2], xv[3]); else L1_STEP(1, 0, true);
        __syncthreads();
    }

    // ---- main loop k=2..511 ----
    for (int k = 2; k < TSTEPS; k += 2) {
        const f32x4 xv = *(const f32x4*)&x_lds[xoff + k * 2];
        if (!isL1) L0_STEP(0, 1, xv[0], xv[1]); else L1_STEP(0, 1, true);
        __syncthreads();
        if (!isL1) L0_STEP(1, 0, xv[2], xv[3]); else L1_STEP(1, 0, true);
        __syncthreads();
    }

    // ---- peeled k=512: H0[512] slot 0, H1[511] slot 0 -> h1f32 ----
    if (isL1) {
        f16x8 a0  = *(const f16x8*)&h0_lds[0][arow];
        f16x8 a1  = *(const f16x8*)&h0_lds[0][arow + 32];
        f16x8 b0v = *(const f16x8*)&h1_lds[0][arow];
        f16x8 b1v = *(const f16x8*)&h1_lds[0][arow + 32];
        f32x4 A[2];
        #pragma unroll
        for (int t = 0; t < 2; ++t) A[t] = MFMA16(a0, wf[t][0], cbv[t]);
        #pragma unroll
        for (int t = 0; t < 2; ++t) A[t] = MFMA16(a1, wf[t][1], A[t]);
        #pragma unroll
        for (int t = 0; t < 2; ++t) A[t] = MFMA16(b0v, wf[t][2], A[t]);
        #pragma unroll
        for (int t = 0; t < 2; ++t) A[t] = MFMA16(b1v, wf[t][3], A[t]);
        float r0a = rcp1p(A[0][0]), r0b = rcp1p(A[0][2]);
        float r1a = rcp1p(A[1][0]), r1b = rcp1p(A[1][2]);
        float va = fmaf(selA, r1a, selB), vb = fmaf(selA, r1b, selB);
        float sa = __shfl_xor(r0a * va, 8);
        float sb = __shfl_xor(r0b * vb, 8);
        c0 = fmaf(r0a, c0, sa);  c1 = fmaf(r0b, c1, sb);
        float ha = va * (1.f - 2.f * rcp1p(c0 * KTANH));
        float hb = vb * (1.f - 2.f * rcp1p(c1 * KTANH));
        if (!lo) {
            h1f32[(quad * 2) * HID + uu]     = ha;
            h1f32[(quad * 2 + 1) * HID + uu] = hb;
        }
    }
    __syncthreads();

    // ---- epilogue: features = relu(H1[512] @ fcW^T + fcb) ----
    if (tid < MB * 32) {
        const int o  = tid & 31;
        const int rr = tid >> 5;
        float acc = fcb_lds[o];
        #pragma unroll 8
        for (int kk = 0; kk < HID; ++kk)
            acc += h1f32[rr * HID + kk] * fcw_lds[kk * 32 + o];
        out[(bbase + rr) * 32 + o] = fmaxf(acc, 0.f);
    }
}

extern "C" void kernel_launch(void* const* d_in, const int* in_sizes, int n_in,
                              void* d_out, int out_size, void* d_ws, size_t ws_size,
                              hipStream_t stream) {
    const float* x    = (const float*)d_in[0];
    const float* Wih0 = (const float*)d_in[1];
    const float* Whh0 = (const float*)d_in[2];
    const float* bih0 = (const float*)d_in[3];
    const float* bhh0 = (const float*)d_in[4];
    const float* Wih1 = (const float*)d_in[5];
    const float* Whh1 = (const float*)d_in[6];
    const float* bih1 = (const float*)d_in[7];
    const float* bhh1 = (const float*)d_in[8];
    const float* fcW  = (const float*)d_in[9];
    const float* fcb  = (const float*)d_in[10];
    float* out = (float*)d_out;

    lstm_feat_kernel<<<2048 / MB, 1024, 0, stream>>>(
        x, Wih0, Whh0, bih0, bhh0, Wih1, Whh1, bih1, bhh1, fcW, fcb, out);
}

// Round 10
// 370.913 us; speedup vs baseline: 1.0064x; 1.0064x over previous
//
#include <hip/hip_runtime.h>
#include <hip/hip_bf16.h>

// LSTMFeatureExtractor: 2-layer LSTM (H=64, IN=1, B=2048, T=512) + FC(64->32)+ReLU
// R14 = homogeneous waves with INTRA-wave dual chains (resubmit: R9 bench was
// a GPUAcquisitionTimeout, no data). Evidence: MFMA floor 466cy/SIMD/step
// (invariant R7-R13), VALU ~500-650; R8 runs them serially (1331cy); R12
// (inter-wave anti-phase) and R13 (more waves, duplicated VALU) both failed.
// Fix: every wave = one L0 slice (4 MFMA, gate-pair packed t0=i|f t1=g|o) +
// one L1 slice (8 MFMA, 4-chains, bias in C) -- two INDEPENDENT chains per
// wave -> its L1 MFMA burst overlaps its L0 cell VALU without barriers;
// 8 homogeneous waves -> balanced barrier arrival.
// Cells: full per-lane (lane nq<8 -> (b=2q,u), nq>=8 -> (2q+1,u)); gates
// completed by 2 shfl_xor(8)/slice (no duplicated trans -- R13's flaw).
// H0 = 4-slot ring (L1 reads n-1, L0 writes n+1: always distinct), H1 = 2.
// 1 barrier/interval. Same total MFMA (12/wave) and cell VALU (2 cells/lane).

#define HID 64
#define TSTEPS 512
#define MB 8
#define RS 80   // f16 row stride: 160B

typedef _Float16 f16x8 __attribute__((ext_vector_type(8)));
typedef float f32x4 __attribute__((ext_vector_type(4)));

#define KSIG (-1.44269504089f)   // -log2(e)
#define KTANH (2.88539008178f)   // 2*log2(e)

__device__ __forceinline__ float rcp1p(float p) {   // 1/(1+2^p)
    return __builtin_amdgcn_rcpf(1.f + __builtin_amdgcn_exp2f(p));
}

#define MFMA16(A, B, C) __builtin_amdgcn_mfma_f32_16x16x32_f16((A), (B), (C), 0, 0, 0)

__global__ __launch_bounds__(512, 1) void lstm_feat_kernel(
    const float* __restrict__ x,
    const float* __restrict__ Wih0, const float* __restrict__ Whh0,
    const float* __restrict__ bih0, const float* __restrict__ bhh0,
    const float* __restrict__ Wih1, const float* __restrict__ Whh1,
    const float* __restrict__ bih1, const float* __restrict__ bhh1,
    const float* __restrict__ fcW, const float* __restrict__ fcb,
    float* __restrict__ out)
{
    __shared__ __align__(16) float x_lds[4 * TSTEPS * 2];    // [qp][t][2], 16 KB
    __shared__ __align__(16) _Float16 h0_lds[4][MB * RS];    // H0[t] ring, slot t&3
    __shared__ __align__(16) _Float16 h1_lds[2][MB * RS];    // H1[s] ring, slot s&1
    __shared__ float h1f32[MB * HID];
    __shared__ float fcw_lds[HID * 32];                      // transposed [k][o]
    __shared__ float fcb_lds[32];

    const int tid  = threadIdx.x;
    const int wave = tid >> 6;          // 0..7
    const int lane = tid & 63;
    const int nq   = lane & 15;
    const int quad = lane >> 4;
    const int oct  = wave * 8;          // this wave's 8 units (both layers)
    const bool lo  = (nq < 8);
    const int bbase = blockIdx.x * MB;

    // ---- one-time staging ----
    for (int i = tid; i < TSTEPS * MB; i += 512) {
        int r = i >> 9, t = i & (TSTEPS - 1);
        x_lds[(r >> 1) * (TSTEPS * 2) + t * 2 + (r & 1)] = x[(bbase + r) * TSTEPS + t];
    }
    for (int i = tid; i < 32 * HID; i += 512) {
        int o = i >> 6, kk = i & 63;
        fcw_lds[kk * 32 + o] = fcW[i];
    }
    if (tid < 32) fcb_lds[tid] = fcb[tid];
    for (int i = tid; i < 4 * MB * RS; i += 512) ((_Float16*)h0_lds)[i] = (_Float16)0.f;
    for (int i = tid; i < 2 * MB * RS; i += 512) ((_Float16*)h1_lds)[i] = (_Float16)0.f;

    // ---- per-lane columns: tile t in {0,1}; col gate = 2t+(nq>>3), unit = oct+(nq&7)
    //      (PyTorch gate order i,f,g,o: t0 = i|f, t1 = g|o). All PRE-SCALED. ----
    f16x8 w0[2][2], wi1[2][2], wh1[2][2];
    float bs0[2], wx0[2];
    f32x4 cb1[2];
    #pragma unroll
    for (int t = 0; t < 2; ++t) {
        const int gate = 2 * t + (nq >> 3);
        const int n = gate * 64 + oct + (nq & 7);
        const float sc = (gate == 2) ? KTANH : KSIG;
        bs0[t] = (bih0[n] + bhh0[n]) * sc;
        wx0[t] = Wih0[n] * sc;                      // IN==1
        const float cb = (bih1[n] + bhh1[n]) * sc;
        cb1[t] = (f32x4){cb, cb, cb, cb};
        #pragma unroll
        for (int ks = 0; ks < 2; ++ks) {
            const int k0 = quad * 8 + ks * 32;
            f16x8 a, b, c;
            #pragma unroll
            for (int j = 0; j < 8; ++j) {
                a[j] = (_Float16)(Whh0[n * HID + k0 + j] * sc);
                b[j] = (_Float16)(Wih1[n * HID + k0 + j] * sc);
                c[j] = (_Float16)(Whh1[n * HID + k0 + j] * sc);
            }
            w0[t][ks] = a; wi1[t][ks] = b; wh1[t][ks] = c;
        }
    }

    // A row m carries h[m>>1] (r=2); lane reads A-row nq. D: elem e = row
    // quad*4+e -> batch 2q+(e>>1): elems 0,2 used.
    const int arow = (nq >> 1) * RS + quad * 8;
    // cell identity: lane -> (b = 2q + (lo?0:1), u = oct + (nq&7))
    const int wrow = (quad * 2 + (lo ? 0 : 1)) * RS + oct + (nq & 7);
    const int wfc  = (quad * 2 + (lo ? 0 : 1)) * HID + oct + (nq & 7);
    float cl0 = 0.f, cl1 = 0.f;

    __syncthreads();

// ---- L0 matmul: read H0 slot SR, 4 MFMA (2 indep 2-chains); x+bias in C ----
#define L0_MM(SR, X0, X1, OUT) do {                                               \
    f16x8 a0 = *(const f16x8*)&h0_lds[SR][arow];                                  \
    f16x8 a1 = *(const f16x8*)&h0_lds[SR][arow + 32];                             \
    _Pragma("unroll")                                                             \
    for (int t = 0; t < 2; ++t) {                                                 \
        const float c0v = fmaf((X0), wx0[t], bs0[t]);                             \
        const float c1v = fmaf((X1), wx0[t], bs0[t]);                             \
        f32x4 C = {c0v, c0v, c1v, c1v};                                           \
        OUT[t] = MFMA16(a0, w0[t][0], C);                                         \
    }                                                                             \
    _Pragma("unroll")                                                             \
    for (int t = 0; t < 2; ++t) OUT[t] = MFMA16(a1, w0[t][1], OUT[t]);            \
} while (0)

// ---- L1 matmul: H0 slot S0 + H1 slot S1, 8 MFMA (2 indep 4-chains) ----
#define L1_MM(S0, S1, OUT) do {                                                   \
    f16x8 p0 = *(const f16x8*)&h0_lds[S0][arow];                                  \
    f16x8 p1 = *(const f16x8*)&h0_lds[S0][arow + 32];                             \
    f16x8 q0 = *(const f16x8*)&h1_lds[S1][arow];                                  \
    f16x8 q1 = *(const f16x8*)&h1_lds[S1][arow + 32];                             \
    _Pragma("unroll")                                                             \
    for (int t = 0; t < 2; ++t) OUT[t] = MFMA16(p0, wi1[t][0], cb1[t]);           \
    _Pragma("unroll")                                                             \
    for (int t = 0; t < 2; ++t) OUT[t] = MFMA16(p1, wi1[t][1], OUT[t]);           \
    _Pragma("unroll")                                                             \
    for (int t = 0; t < 2; ++t) OUT[t] = MFMA16(q0, wh1[t][0], OUT[t]);           \
    _Pragma("unroll")                                                             \
    for (int t = 0; t < 2; ++t) OUT[t] = MFMA16(q1, wh1[t][1], OUT[t]);           \
} while (0)

// ---- gate exchange (2 shfl) + full per-lane cell ----
// own: lo holds i (t0 e0) and g (t1 e0) for b0; hi holds f (t0 e2), o (t1 e2)
// for b1. shfl_xor(8) swaps the complementary halves.
#define CELLX(AC, CST, HOUT) do {                                                 \
    float r1 = __shfl_xor(lo ? AC[0][2] : AC[0][0], 8);                           \
    float r2 = __shfl_xor(lo ? AC[1][2] : AC[1][0], 8);                           \
    float pi = lo ? AC[0][0] : r1;                                                \
    float pf = lo ? r1 : AC[0][2];                                                \
    float pg = lo ? AC[1][0] : r2;                                                \
    float po = lo ? r2 : AC[1][2];                                                \
    float iv = rcp1p(pi), fv = rcp1p(pf), ov = rcp1p(po);                         \
    float gv = 1.f - 2.f * rcp1p(pg);                                             \
    CST = fmaf(fv, CST, iv * gv);                                                 \
    HOUT = ov * (1.f - 2.f * rcp1p(CST * KTANH));                                 \
} while (0)

// ---- full interval n (NM4 = n&3 compile-time): L0-step n + L1-step n-1 ----
#define IV_FULL(NM4, X0, X1) do {                                                 \
    f32x4 A0[2], A1[2];                                                           \
    __builtin_amdgcn_s_setprio(1);                                                \
    L0_MM((NM4) & 3, X0, X1, A0);                                                 \
    L1_MM(((NM4) + 3) & 3, (NM4) & 1, A1);                                        \
    __builtin_amdgcn_s_setprio(0);                                                \
    float h0v, h1v;                                                               \
    CELLX(A0, cl0, h0v);                                                          \
    h0_lds[((NM4) + 1) & 3][wrow] = (_Float16)h0v;                                \
    CELLX(A1, cl1, h1v);                                                          \
    h1_lds[((NM4) + 1) & 1][wrow] = (_Float16)h1v;                                \
    __syncthreads();                                                              \
} while (0)

// ---- L0-only interval (prologue n=0,1) ----
#define IV_L0(NM4, X0, X1) do {                                                   \
    f32x4 A0[2];                                                                  \
    __builtin_amdgcn_s_setprio(1);                                                \
    L0_MM((NM4) & 3, X0, X1, A0);                                                 \
    __builtin_amdgcn_s_setprio(0);                                                \
    float h0v;                                                                    \
    CELLX(A0, cl0, h0v);                                                          \
    h0_lds[((NM4) + 1) & 3][wrow] = (_Float16)h0v;                                \
    __syncthreads();                                                              \
} while (0)

    const int xoff = quad * (TSTEPS * 2);

    // ---- prologue intervals n=0..3 ----
    {
        const f32x4 xv0 = *(const f32x4*)&x_lds[xoff + 0];   // t=0,1
        const f32x4 xv1 = *(const f32x4*)&x_lds[xoff + 4];   // t=2,3
        IV_L0(0, xv0[0], xv0[1]);
        IV_L0(1, xv0[2], xv0[3]);
        IV_FULL(2, xv1[0], xv1[1]);   // first L1 step (s=1): h0[1] slot1, h1[0] slot0
        IV_FULL(3, xv1[2], xv1[3]);
    }

    // ---- main loop: intervals n=4..511 ----
    for (int n = 4; n < TSTEPS; n += 4) {
        const f32x4 xv0 = *(const f32x4*)&x_lds[xoff + n * 2];
        const f32x4 xv1 = *(const f32x4*)&x_lds[xoff + n * 2 + 4];
        IV_FULL(0, xv0[0], xv0[1]);
        IV_FULL(1, xv0[2], xv0[3]);
        IV_FULL(2, xv1[0], xv1[1]);
        IV_FULL(3, xv1[2], xv1[3]);
    }

    // ---- epilogue n=512: L1 step 511 (h0[511] slot3, h1[510] slot0) ----
    {
        f32x4 A1[2];
        L1_MM(3, 0, A1);
        float h1v;
        CELLX(A1, cl1, h1v);
        h1_lds[1][wrow] = (_Float16)h1v;       // h1[511] slot 1
    }
    __syncthreads();
    // ---- epilogue n=513: L1 step 512 (h0[512] slot0, h1[511] slot1) ----
    {
        f32x4 A1[2];
        L1_MM(0, 1, A1);
        float h1v;
        CELLX(A1, cl1, h1v);
        h1f32[wfc] = h1v;                      // final h1[512], f32
    }
    __syncthreads();

    // ---- epilogue: features = relu(H1[512] @ fcW^T + fcb) ----
    if (tid < MB * 32) {
        const int o  = tid & 31;
        const int rr = tid >> 5;
        float acc = fcb_lds[o];
        #pragma unroll 8
        for (int kk = 0; kk < HID; ++kk)
            acc += h1f32[rr * HID + kk] * fcw_lds[kk * 32 + o];
        out[(bbase + rr) * 32 + o] = fmaxf(acc, 0.f);
    }
}

extern "C" void kernel_launch(void* const* d_in, const int* in_sizes, int n_in,
                              void* d_out, int out_size, void* d_ws, size_t ws_size,
                              hipStream_t stream) {
    const float* x    = (const float*)d_in[0];
    const float* Wih0 = (const float*)d_in[1];
    const float* Whh0 = (const float*)d_in[2];
    const float* bih0 = (const float*)d_in[3];
    const float* bhh0 = (const float*)d_in[4];
    const float* Wih1 = (const float*)d_in[5];
    const float* Whh1 = (const float*)d_in[6];
    const float* bih1 = (const float*)d_in[7];
    const float* bhh1 = (const float*)d_in[8];
    const float* fcW  = (const float*)d_in[9];
    const float* fcb  = (const float*)d_in[10];
    float* out = (float*)d_out;

    lstm_feat_kernel<<<2048 / MB, 512, 0, stream>>>(
        x, Wih0, Whh0, bih0, bhh0, Wih1, Whh1, bih1, bhh1, fcW, fcb, out);
}

// Round 11
// 304.672 us; speedup vs baseline: 1.2252x; 1.2174x over previous
//
#include <hip/hip_runtime.h>
#include <hip/hip_bf16.h>

// LSTMFeatureExtractor: 2-layer LSTM (H=64, IN=1, B=2048, T=512) + FC(64->32)+ReLU
// R15 = R8 (best, 284us) + algebraic trans fusion. Model: R8's 1331cy step =
// MFMA 466 + trans-dominated cell ~500-640 (40 wave-trans-instr/SIMD/step at
// quarter-rate) + ~250 overhead, phases serialized (all structural overlap
// attempts R9-R14 failed). Lever: cut trans per cell 10 -> 7:
//   c' = [c*A*Gp + (G-1)*B] * rcp(A*B*Gp)   (one rcp for i,f,g gates)
//   h  = (E-1) * rcp(Dn*(E+1)), E=2^(KT*c') (one rcp for o*tanh)
// where A=1+2^pi, B=1+2^pf, G=2^pg, Dn=1+2^po (pre-acts prescaled as before).
// Everything else identical to R8: wave-specialized L0/L1, prescaled weights,
// bias in MFMA C, packed f32x2 cells, k-unroll x2, setprio.

#define HID 64
#define TSTEPS 512
#define MB 8
#define RS 80   // f16 row stride: 160B

typedef _Float16 f16x8 __attribute__((ext_vector_type(8)));
typedef float f32x4 __attribute__((ext_vector_type(4)));
typedef float f32x2 __attribute__((ext_vector_type(2)));

#define KSIG (-1.44269504089f)   // -log2(e)
#define KTANH (2.88539008178f)   // 2*log2(e)

__device__ __forceinline__ f32x2 mk2(float a, float b) { f32x2 r; r[0] = a; r[1] = b; return r; }
__device__ __forceinline__ f32x2 exp2v(f32x2 v) {
    f32x2 r; r[0] = __builtin_amdgcn_exp2f(v[0]); r[1] = __builtin_amdgcn_exp2f(v[1]); return r;
}
__device__ __forceinline__ f32x2 rcpv(f32x2 v) {
    f32x2 r; r[0] = __builtin_amdgcn_rcpf(v[0]); r[1] = __builtin_amdgcn_rcpf(v[1]); return r;
}

__global__ __launch_bounds__(512, 1) void lstm_feat_kernel(
    const float* __restrict__ x,
    const float* __restrict__ Wih0, const float* __restrict__ Whh0,
    const float* __restrict__ bih0, const float* __restrict__ bhh0,
    const float* __restrict__ Wih1, const float* __restrict__ Whh1,
    const float* __restrict__ bih1, const float* __restrict__ bhh1,
    const float* __restrict__ fcW, const float* __restrict__ fcb,
    float* __restrict__ out)
{
    __shared__ float x_lds[(MB / 2) * TSTEPS * 2];          // [qp][t][2], 16 KB
    __shared__ __align__(16) _Float16 h0_lds[2][MB * RS];
    __shared__ __align__(16) _Float16 h1_lds[2][MB * RS];
    __shared__ float h1f32[MB * HID];
    __shared__ float fcw_lds[HID * 32];                     // transposed [k][o]
    __shared__ float fcb_lds[32];

    const int tid  = threadIdx.x;
    const int wave = tid >> 6;
    const int lane = tid & 63;
    const int nq   = lane & 15;
    const int quad = lane >> 4;
    const int bbase = blockIdx.x * MB;
    const bool isL1 = (wave >= 4);     // waves 0-3: layer0, waves 4-7: layer1
    const int ug = wave & 3;
    const int u  = ug * 16 + nq;       // hidden unit owned by this lane

    // ---- one-time staging ----
    for (int i = tid; i < TSTEPS * MB; i += 512) {
        int r = i >> 9, t = i & (TSTEPS - 1);
        x_lds[(r >> 1) * (TSTEPS * 2) + t * 2 + (r & 1)] = x[(bbase + r) * TSTEPS + t];
    }
    for (int i = tid; i < 32 * HID; i += 512) {
        int o = i >> 6, kk = i & 63;
        fcw_lds[kk * 32 + o] = fcW[i];
    }
    if (tid < 32) fcb_lds[tid] = fcb[tid];
    for (int i = tid; i < 2 * MB * RS; i += 512) {
        ((_Float16*)h0_lds)[i] = (_Float16)0.f;
        ((_Float16*)h1_lds)[i] = (_Float16)0.f;
    }

    // ---- per-lane weight fragments, PRE-SCALED by gate constant ----
    // L0 waves: wA = Whh0. L1 waves: wA = Wih1, wB = Whh1.
    f16x8 wA[4][2], wB[4][2];
    f32x4 cbias[4];                    // scaled bias splat -> MFMA C operand
    float wx0s[4];
    {
        const float* Wa = isL1 ? Wih1 : Whh0;
        const float* Wb = isL1 ? Whh1 : Whh0;
        const float* bi = isL1 ? bih1 : bih0;
        const float* bh = isL1 ? bhh1 : bhh0;
        #pragma unroll
        for (int g = 0; g < 4; ++g) {
            const float sc = (g == 2) ? KTANH : KSIG;
            const int n = g * 64 + u;
            const float bs = (bi[n] + bh[n]) * sc;
            cbias[g] = (f32x4){bs, bs, bs, bs};
            wx0s[g] = Wih0[n] * sc;    // IN==1 (L0 waves only)
            #pragma unroll
            for (int ks = 0; ks < 2; ++ks) {
                const int k0 = quad * 8 + ks * 32;
                f16x8 a, b;
                #pragma unroll
                for (int j = 0; j < 8; ++j) {
                    a[j] = (_Float16)(Wa[n * HID + k0 + j] * sc);
                    b[j] = (_Float16)(Wb[n * HID + k0 + j] * sc);
                }
                wA[g][ks] = a; wB[g][ks] = b;
            }
        }
    }

    const f32x4 zero4 = {0.f, 0.f, 0.f, 0.f};
    // A row m carries h[m>>1]; D row quad*4+reg -> batch (quad*4+reg)>>1:
    // regs {0,1}->b0 (use elem 0), {2,3}->b0+1 (use elem 2).
    const int arow = (nq >> 1) * RS + quad * 8;
    const int b0r  = (quad * 2) * RS;  // byte-row of this lane's first batch
    const int hbase = quad * 2;        // first batch row index
    f32x2 cc = mk2(0.f, 0.f);          // packed cell state (both batch rows)

    __syncthreads();

// ---- fused cell: pre-acts PI,PF,PG,PO (packed, prescaled) -> updates cc,
//      produces hh. 7 trans/cell: 5 exp2 + 2 rcp. ----
#define FCELL(PI, PF, PG, PO, HH) do {                                               \
    f32x2 ea = exp2v(PI), eb = exp2v(PF), eg = exp2v(PG), ed = exp2v(PO);            \
    f32x2 Aq = ea + 1.f, Bq = eb + 1.f, Gp = eg + 1.f, Dn = ed + 1.f;                \
    f32x2 AG = Aq * Gp;                                                              \
    f32x2 r1 = rcpv(AG * Bq);                                                        \
    f32x2 nm = cc * AG + (eg - 1.f) * Bq;                                            \
    cc = nm * r1;                                                                    \
    f32x2 E  = exp2v(cc * KTANH);                                                    \
    f32x2 r2 = rcpv(Dn * (E + 1.f));                                                 \
    HH = (E - 1.f) * r2;                                                             \
} while (0)

// ---- one layer-0 substep, compile-time buffers P->Q ----
#define L0_SUB(P, Q, XQ2) do {                                                       \
    f16x8 a0_ = *(const f16x8*)&h0_lds[P][arow];                                     \
    f16x8 a1_ = *(const f16x8*)&h0_lds[P][arow + 32];                                \
    f32x4 ac[4];                                                                     \
    __builtin_amdgcn_s_setprio(1);                                                   \
    _Pragma("unroll")                                                                \
    for (int g = 0; g < 4; ++g)                                                      \
        ac[g] = __builtin_amdgcn_mfma_f32_16x16x32_f16(a0_, wA[g][0], cbias[g], 0, 0, 0); \
    _Pragma("unroll")                                                                \
    for (int g = 0; g < 4; ++g)                                                      \
        ac[g] = __builtin_amdgcn_mfma_f32_16x16x32_f16(a1_, wA[g][1], ac[g], 0, 0, 0); \
    __builtin_amdgcn_s_setprio(0);                                                   \
    f32x2 pi = (XQ2) * wx0s[0] + mk2(ac[0][0], ac[0][2]);                            \
    f32x2 pf = (XQ2) * wx0s[1] + mk2(ac[1][0], ac[1][2]);                            \
    f32x2 pg = (XQ2) * wx0s[2] + mk2(ac[2][0], ac[2][2]);                            \
    f32x2 po = (XQ2) * wx0s[3] + mk2(ac[3][0], ac[3][2]);                            \
    f32x2 hh;                                                                        \
    FCELL(pi, pf, pg, po, hh);                                                       \
    h0_lds[Q][b0r + u]      = (_Float16)hh[0];                                       \
    h0_lds[Q][b0r + RS + u] = (_Float16)hh[1];                                       \
} while (0)

// ---- one layer-1 substep; GUARD=false suppresses the k==0 commit ----
#define L1_SUB(P, Q, GUARD) do {                                                     \
    f16x8 a00 = *(const f16x8*)&h0_lds[P][arow];                                     \
    f16x8 a01 = *(const f16x8*)&h0_lds[P][arow + 32];                                \
    f16x8 a10 = *(const f16x8*)&h1_lds[P][arow];                                     \
    f16x8 a11 = *(const f16x8*)&h1_lds[P][arow + 32];                                \
    f32x4 aA[4], aB[4];                                                              \
    __builtin_amdgcn_s_setprio(1);                                                   \
    _Pragma("unroll")                                                                \
    for (int g = 0; g < 4; ++g)                                                      \
        aA[g] = __builtin_amdgcn_mfma_f32_16x16x32_f16(a00, wA[g][0], zero4, 0, 0, 0); \
    _Pragma("unroll")                                                                \
    for (int g = 0; g < 4; ++g)                                                      \
        aB[g] = __builtin_amdgcn_mfma_f32_16x16x32_f16(a10, wB[g][0], cbias[g], 0, 0, 0); \
    _Pragma("unroll")                                                                \
    for (int g = 0; g < 4; ++g)                                                      \
        aA[g] = __builtin_amdgcn_mfma_f32_16x16x32_f16(a01, wA[g][1], aA[g], 0, 0, 0); \
    _Pragma("unroll")                                                                \
    for (int g = 0; g < 4; ++g)                                                      \
        aB[g] = __builtin_amdgcn_mfma_f32_16x16x32_f16(a11, wB[g][1], aB[g], 0, 0, 0); \
    __builtin_amdgcn_s_setprio(0);                                                   \
    if (GUARD) {                                                                     \
        f32x2 pi = mk2(aA[0][0], aA[0][2]) + mk2(aB[0][0], aB[0][2]);                \
        f32x2 pf = mk2(aA[1][0], aA[1][2]) + mk2(aB[1][0], aB[1][2]);                \
        f32x2 pg = mk2(aA[2][0], aA[2][2]) + mk2(aB[2][0], aB[2][2]);                \
        f32x2 po = mk2(aA[3][0], aA[3][2]) + mk2(aB[3][0], aB[3][2]);                \
        f32x2 hh;                                                                    \
        FCELL(pi, pf, pg, po, hh);                                                   \
        h1_lds[Q][b0r + u]      = (_Float16)hh[0];                                   \
        h1_lds[Q][b0r + RS + u] = (_Float16)hh[1];                                   \
    }                                                                                \
} while (0)

    // ---- skewed recurrence, unrolled x2 (buffers 0->1 then 1->0) ----
    const int xoff = quad * (TSTEPS * 2);
    for (int k = 0; k < TSTEPS; k += 2) {
        f32x2 xa, xb;
        if (!isL1) {
            const f32x4 xv = *(const f32x4*)&x_lds[xoff + k * 2];
            xa = mk2(xv[0], xv[1]); xb = mk2(xv[2], xv[3]);
            L0_SUB(0, 1, xa);
        } else {
            L1_SUB(0, 1, (k > 0));
        }
        __syncthreads();
        if (!isL1) {
            L0_SUB(1, 0, xb);
        } else {
            L1_SUB(1, 0, true);
        }
        __syncthreads();
    }

    // ---- peeled final layer-1 step: H1[512] from H0[512] (buf 0), H1[511] ----
    if (isL1) {
        f16x8 a00 = *(const f16x8*)&h0_lds[0][arow];
        f16x8 a01 = *(const f16x8*)&h0_lds[0][arow + 32];
        f16x8 a10 = *(const f16x8*)&h1_lds[0][arow];
        f16x8 a11 = *(const f16x8*)&h1_lds[0][arow + 32];
        f32x4 aA[4], aB[4];
        #pragma unroll
        for (int g = 0; g < 4; ++g)
            aA[g] = __builtin_amdgcn_mfma_f32_16x16x32_f16(a00, wA[g][0], zero4, 0, 0, 0);
        #pragma unroll
        for (int g = 0; g < 4; ++g)
            aB[g] = __builtin_amdgcn_mfma_f32_16x16x32_f16(a10, wB[g][0], cbias[g], 0, 0, 0);
        #pragma unroll
        for (int g = 0; g < 4; ++g)
            aA[g] = __builtin_amdgcn_mfma_f32_16x16x32_f16(a01, wA[g][1], aA[g], 0, 0, 0);
        #pragma unroll
        for (int g = 0; g < 4; ++g)
            aB[g] = __builtin_amdgcn_mfma_f32_16x16x32_f16(a11, wB[g][1], aB[g], 0, 0, 0);
        f32x2 pi = mk2(aA[0][0], aA[0][2]) + mk2(aB[0][0], aB[0][2]);
        f32x2 pf = mk2(aA[1][0], aA[1][2]) + mk2(aB[1][0], aB[1][2]);
        f32x2 pg = mk2(aA[2][0], aA[2][2]) + mk2(aB[2][0], aB[2][2]);
        f32x2 po = mk2(aA[3][0], aA[3][2]) + mk2(aB[3][0], aB[3][2]);
        f32x2 hh;
        FCELL(pi, pf, pg, po, hh);
        h1f32[hbase * HID + u]       = hh[0];
        h1f32[(hbase + 1) * HID + u] = hh[1];
    }
    __syncthreads();

    // ---- epilogue: features = relu(H1[512] @ fcW^T + fcb) ----
    if (tid < MB * 32) {
        const int o  = tid & 31;
        const int rr = tid >> 5;
        float acc = fcb_lds[o];
        #pragma unroll 8
        for (int kk = 0; kk < HID; ++kk)
            acc += h1f32[rr * HID + kk] * fcw_lds[kk * 32 + o];
        out[(bbase + rr) * 32 + o] = fmaxf(acc, 0.f);
    }
}

extern "C" void kernel_launch(void* const* d_in, const int* in_sizes, int n_in,
                              void* d_out, int out_size, void* d_ws, size_t ws_size,
                              hipStream_t stream) {
    const float* x    = (const float*)d_in[0];
    const float* Wih0 = (const float*)d_in[1];
    const float* Whh0 = (const float*)d_in[2];
    const float* bih0 = (const float*)d_in[3];
    const float* bhh0 = (const float*)d_in[4];
    const float* Wih1 = (const float*)d_in[5];
    const float* Whh1 = (const float*)d_in[6];
    const float* bih1 = (const float*)d_in[7];
    const float* bhh1 = (const float*)d_in[8];
    const float* fcW  = (const float*)d_in[9];
    const float* fcb  = (const float*)d_in[10];
    float* out = (float*)d_out;

    lstm_feat_kernel<<<2048 / MB, 512, 0, stream>>>(
        x, Wih0, Whh0, bih0, bhh0, Wih1, Whh1, bih1, bhh1, fcW, fcb, out);
}